// Round 6
// baseline (198.753 us; speedup 1.0000x reference)
//
#include <hip/hip_runtime.h>
#include <hip/hip_bf16.h>

// Shapes
#define NG 16
#define NN 2048
#define NF 32
#define NE 32768
#define IND 65536   // NN*NF
#define HD 512
#define LD 64

typedef unsigned int u32;

// ---------------- GCN part ----------------

// xw = x @ W_gcn   (per flat node)
__global__ void k_xw(const float* __restrict__ x, const float* __restrict__ Wg,
                     float* __restrict__ xw){
  __shared__ float ws[32][33];
  __shared__ float xsh[8][32];
  int t = threadIdx.x;
  for (int i = t; i < 1024; i += 256) ws[i >> 5][i & 31] = Wg[i];
  int base = blockIdx.x * 8;            // flat node index (g*NN+n)
  int r = t >> 5, f = t & 31;
  xsh[r][f] = x[(base + r) * 32 + f];
  __syncthreads();
  float acc = 0.f;
  #pragma unroll
  for (int k = 0; k < 32; ++k) acc += xsh[r][k] * ws[k][f];
  xw[(base + r) * 32 + f] = acc;
}

// fused: deg histogram + exclusive scan + counting-sort, one block per graph
__global__ __launch_bounds__(1024) void k_buildcsr(const int* __restrict__ ei,
    u32* __restrict__ offs, u32* __restrict__ deg, float* __restrict__ dinv,
    u32* __restrict__ sorted){
  int g = blockIdx.x, t = threadIdx.x;
  __shared__ u32 hist[2048];
  __shared__ u32 cur[2048];
  __shared__ u32 ssum[1024];
  hist[t] = 0u; hist[t + 1024] = 0u;
  __syncthreads();
  const int* dstp = ei + g * 2 * NE + NE;
  for (int e = t; e < NE; e += 1024) atomicAdd(&hist[dstp[e]], 1u);
  __syncthreads();
  // scan: thread t owns bins 2t, 2t+1
  u32 a = hist[2 * t], b = hist[2 * t + 1];
  u32 s = a + b;
  ssum[t] = s;
  __syncthreads();
  for (int d = 1; d < 1024; d <<= 1){
    u32 v = (t >= d) ? ssum[t - d] : 0u;
    __syncthreads();
    ssum[t] += v;
    __syncthreads();
  }
  u32 base = ssum[t] - s;                  // exclusive over bin pairs
  cur[2 * t] = base;
  cur[2 * t + 1] = base + a;
  __syncthreads();
  for (int n = t; n < 2048; n += 1024){
    u32 d0 = hist[n];
    offs[g * NN + n] = g * NE + cur[n];    // absolute CSR start
    deg [g * NN + n] = d0;
    dinv[g * NN + n] = rsqrtf((float)(d0 + 1u));  // +1 self loop
  }
  __syncthreads();
  const int* srcp = ei + g * 2 * NE;
  for (int e = t; e < NE; e += 1024){
    int dst = dstp[e];
    u32 pos = atomicAdd(&cur[dst], 1u);    // graph-local position
    sorted[g * NE + pos] = (u32)srcp[e];
  }
}

// gather: h[g][n][f] = sum_{src->n} dinv[src]*dinv[n]*xw[src][f] + dinv[n]^2*xw[n][f] + bg[f]
__global__ void k_gather(const u32* __restrict__ sorted, const u32* __restrict__ offs,
                         const u32* __restrict__ deg, const float* __restrict__ dinv,
                         const float* __restrict__ xw, const float* __restrict__ bg,
                         float* __restrict__ h){
  int tid = blockIdx.x * 256 + threadIdx.x;   // < NG*NN*4
  int qp = tid & 3, n = (tid >> 2) & (NN - 1), g = tid >> 13;
  int gn = g * NN + n;
  u32 o0 = offs[gn];
  u32 cnt = deg[gn];
  float dn = dinv[gn];
  const float4* xw4 = (const float4*)xw;
  float4 a0 = make_float4(0.f,0.f,0.f,0.f), a1 = a0;
  for (u32 e = 0; e < cnt; ++e){
    u32 src = sorted[o0 + e];
    float c = dinv[g * NN + src] * dn;
    const float4* xr = xw4 + (size_t)(g * NN + src) * 8 + qp * 2;
    float4 v0 = xr[0], v1 = xr[1];
    a0.x += c*v0.x; a0.y += c*v0.y; a0.z += c*v0.z; a0.w += c*v0.w;
    a1.x += c*v1.x; a1.y += c*v1.y; a1.z += c*v1.z; a1.w += c*v1.w;
  }
  float c2 = dn * dn;
  const float4* xr = xw4 + (size_t)gn * 8 + qp * 2;
  float4 v0 = xr[0], v1 = xr[1];
  float4 b0 = ((const float4*)bg)[qp * 2], b1 = ((const float4*)bg)[qp * 2 + 1];
  a0.x += c2*v0.x + b0.x; a0.y += c2*v0.y + b0.y; a0.z += c2*v0.z + b0.z; a0.w += c2*v0.w + b0.w;
  a1.x += c2*v1.x + b1.x; a1.y += c2*v1.y + b1.y; a1.z += c2*v1.z + b1.z; a1.w += c2*v1.w + b1.w;
  float4* hp = (float4*)h + (size_t)gn * 8 + qp * 2;
  hp[0] = a0; hp[1] = a1;
}

// ---------------- BatchNorm: final scale/shift per (g,f), one block per graph ----------------

__global__ __launch_bounds__(1024) void k_bnfin(const float* __restrict__ h,
    const float* __restrict__ gamma, const float* __restrict__ beta,
    float* __restrict__ scale, float* __restrict__ shift){
  int g = blockIdx.x, t = threadIdx.x;
  float s1 = 0.f, s2 = 0.f;
  const float* hp = h + (size_t)g * IND;
  for (int i = 0; i < 64; ++i){
    float v = hp[i * 1024 + t];            // n = i*32 + (t>>5), f = t&31
    s1 += v; s2 += v * v;
  }
  __shared__ float l1[1024], l2[1024];
  l1[t] = s1; l2[t] = s2;
  __syncthreads();
  for (int d = 512; d >= 32; d >>= 1){
    if (t < d){ l1[t] += l1[t + d]; l2[t] += l2[t + d]; }
    __syncthreads();
  }
  if (t < 32){
    float mean = l1[t] * (1.f / NN);
    float var  = l2[t] * (1.f / NN) - mean * mean;
    float sc = gamma[t] * rsqrtf(var + 1e-5f);
    scale[g * 32 + t] = sc;
    shift[g * 32 + t] = beta[t] - mean * sc;
  }
}

// ---------------- Encoder GEMM (tanh-normalize fused): part[512][16][512] ----------------

__global__ __launch_bounds__(256) void k_gemvenc(const float* __restrict__ h,
    const float* __restrict__ scale, const float* __restrict__ shift,
    const float* __restrict__ B, float* __restrict__ part){
  __shared__ float ash[128 * 17];        // padded: write stride 17 avoids conflicts
  __shared__ float ssc[512], ssh[512];
  int t = threadIdx.x;                   // 256 threads
  int k0 = blockIdx.x * 128;             // 512 chunks
  for (int i = t; i < 512; i += 256){ ssc[i] = scale[i]; ssh[i] = shift[i]; }
  __syncthreads();
  for (int idx = t; idx < 2048; idx += 256){
    int i = idx & 127, g = idx >> 7;
    int f = i & 31;                      // (k0+i)&31 == i&31 since 32 | 128 | k0
    float v = h[(size_t)g * IND + k0 + i];
    ash[i * 17 + g] = tanhf(v * ssc[g * 32 + f] + ssh[g * 32 + f]);
  }
  __syncthreads();
  float acc[32];
  #pragma unroll
  for (int i = 0; i < 32; ++i) acc[i] = 0.f;
  const float2* bp = (const float2*)(B + (size_t)k0 * 512) + t;
  for (int kk = 0; kk < 128; kk += 8){
    float2 bv[8];
    #pragma unroll
    for (int u = 0; u < 8; ++u) bv[u] = bp[(size_t)(kk + u) * 256];
    #pragma unroll
    for (int u = 0; u < 8; ++u){
      const float* ap = &ash[(kk + u) * 17];
      #pragma unroll
      for (int m = 0; m < 16; ++m){
        acc[2*m]   += ap[m] * bv[u].x;
        acc[2*m+1] += ap[m] * bv[u].y;
      }
    }
  }
  float* pp = part + (size_t)blockIdx.x * 8192 + t * 2;
  #pragma unroll
  for (int m = 0; m < 16; ++m)
    *(float2*)(pp + (size_t)m * 512) = make_float2(acc[2*m], acc[2*m+1]);
}

// encoder reduce stage1: 512 chunks -> 8 groups of 64
__global__ void k_encred1(const float* __restrict__ part, float* __restrict__ p2){
  int idx = blockIdx.x * 256 + threadIdx.x;   // < 8*8192
  int out = idx & 8191, grp = idx >> 13;
  const float* p = part + (size_t)grp * 64 * 8192 + out;
  float s = 0.f;
  #pragma unroll 8
  for (int c = 0; c < 64; ++c) s += p[(size_t)c * 8192];
  p2[idx] = s;
}

// encoder reduce stage2 + bias + leaky
__global__ void k_encred2(const float* __restrict__ p2, const float* __restrict__ be,
                          float* __restrict__ henc){
  int out = blockIdx.x * 256 + threadIdx.x;   // < 8192
  int n = out & 511;
  float s = be[n];
  #pragma unroll
  for (int g = 0; g < 8; ++g) s += p2[g * 8192 + out];
  henc[out] = s > 0.f ? s : 0.01f * s;
}

// heads + reparameterize + decoder layer1, one block per graph
__global__ __launch_bounds__(512) void k_headdec(const float* __restrict__ henc,
    const float* __restrict__ Wmu, const float* __restrict__ bmu,
    const float* __restrict__ Wlv, const float* __restrict__ blv,
    const float* __restrict__ eps, const float* __restrict__ W1,
    const float* __restrict__ b1, float* __restrict__ hdT, float* __restrict__ outp){
  int g = blockIdx.x, t = threadIdx.x;       // 16 x 512
  __shared__ float hsh[512];
  __shared__ float zsh[64];
  hsh[t] = henc[g * 512 + t];
  __syncthreads();
  int l = t >> 3, r = t & 7;                 // 64 l-slots x 8-way split-K
  float am = 0.f, av = 0.f;
  for (int k = r; k < 512; k += 8){
    float hh = hsh[k];
    am += hh * Wmu[k * 64 + l];
    av += hh * Wlv[k * 64 + l];
  }
  #pragma unroll
  for (int d = 1; d < 8; d <<= 1){
    am += __shfl_xor(am, d);
    av += __shfl_xor(av, d);
  }
  if (r == 0){
    float mean = am + bmu[l];
    float lv   = av + blv[l];
    float z = mean + expf(0.5f * lv) * eps[g * 64 + l];
    zsh[l] = z;
    outp[1048576 + g * 64 + l] = mean;
    outp[1049600 + g * 64 + l] = lv;
  }
  __syncthreads();
  float a = 0.f;
  #pragma unroll
  for (int k = 0; k < 64; ++k) a += zsh[k] * W1[k * 512 + t];
  a += b1[t];
  a = a > 0.f ? a : 0.01f * a;
  hdT[t * 16 + g] = a;
}

// ---------------- Decoder GEMM: K=512 split 4x128, float2 cols ----------------

__global__ __launch_bounds__(256) void k_gemvdec(const float* __restrict__ A,    // [512][16] = hdT
                          const float* __restrict__ B,    // [512][65536] = Wd2
                          float* __restrict__ part){      // [4][16][65536]
  __shared__ float ash[128 * 16];      // 8 KB
  int t = threadIdx.x;                 // 256 threads, float2 cols
  int ks = blockIdx.x & 3;             // 4 k-chunks of 128
  int nb = blockIdx.x >> 2;            // 128 n-tiles of 512
  for (int i = t; i < 2048; i += 256) ash[i] = A[ks * 2048 + i];
  __syncthreads();
  float acc[32];
  #pragma unroll
  for (int i = 0; i < 32; ++i) acc[i] = 0.f;
  const float2* bp = (const float2*)(B + (size_t)ks * 128 * 65536) + nb * 256 + t;
  for (int kk = 0; kk < 128; kk += 8){
    float2 bv[8];
    #pragma unroll
    for (int u = 0; u < 8; ++u) bv[u] = bp[(size_t)(kk + u) * 32768];
    #pragma unroll
    for (int u = 0; u < 8; ++u){
      const float* ap = &ash[(kk + u) * 16];
      #pragma unroll
      for (int m = 0; m < 16; ++m){
        acc[2*m]   += ap[m] * bv[u].x;
        acc[2*m+1] += ap[m] * bv[u].y;
      }
    }
  }
  float* pp = part + (size_t)ks * 1048576 + nb * 512 + t * 2;
  #pragma unroll
  for (int m = 0; m < 16; ++m)
    *(float2*)(pp + (size_t)m * 65536) = make_float2(acc[2*m], acc[2*m+1]);
}

// decoder reduce (4 k-chunks) + bias -> f32 out, float4
__global__ void k_decred(const float4* __restrict__ part, const float4* __restrict__ b2,
                         float4* __restrict__ outp){
  int idx = blockIdx.x * 256 + threadIdx.x;   // < 262144
  int n4 = idx & 16383;
  float4 p0 = part[idx];
  float4 p1 = part[262144 + idx];
  float4 p2 = part[524288 + idx];
  float4 p3 = part[786432 + idx];
  float4 bb = b2[n4];
  float4 o;
  o.x = p0.x + p1.x + p2.x + p3.x + bb.x;
  o.y = p0.y + p1.y + p2.y + p3.y + bb.y;
  o.z = p0.z + p1.z + p2.z + p3.z + bb.z;
  o.w = p0.w + p1.w + p2.w + p3.w + bb.w;
  outp[idx] = o;
}

// ---------------- launch ----------------

extern "C" void kernel_launch(void* const* d_in, const int* in_sizes, int n_in,
                              void* d_out, int out_size, void* d_ws, size_t ws_size,
                              hipStream_t stream){
  const float* x     = (const float*)d_in[0];
  const int*   ei    = (const int*)d_in[1];
  const float* eps   = (const float*)d_in[2];
  const float* Wg    = (const float*)d_in[3];
  const float* bg    = (const float*)d_in[4];
  const float* gamma = (const float*)d_in[5];
  const float* beta  = (const float*)d_in[6];
  const float* Wenc  = (const float*)d_in[7];
  const float* benc  = (const float*)d_in[8];
  const float* Wmu   = (const float*)d_in[9];
  const float* bmu   = (const float*)d_in[10];
  const float* Wlv   = (const float*)d_in[11];
  const float* blv   = (const float*)d_in[12];
  const float* Wd1   = (const float*)d_in[13];
  const float* bd1   = (const float*)d_in[14];
  const float* Wd2   = (const float*)d_in[15];
  const float* bd2   = (const float*)d_in[16];
  float* outp = (float*)d_out;

  char* ws = (char*)d_ws;
  const size_t OFF_XW    = 0;                    // 4 MB
  const size_t OFF_H     = 4194304;              // 4 MB
  const size_t OFF_DEG   = 8388608;              // 128 KB
  const size_t OFF_DINV  = 8519680;              // 128 KB
  const size_t OFF_SCALE = 8650752;              // 2 KB
  const size_t OFF_SHIFT = 8652800;              // 2 KB
  const size_t OFF_HENC  = 8687616;              // 32 KB
  const size_t OFF_HDT   = 8724480;              // 32 KB
  const size_t OFF_P2    = 8757248;              // 256 KB
  const size_t OFF_PART  = 9019392;              // 16 MB (enc/dec partials)
  // aliases inside PART region: dead before k_gemvenc writes part
  const size_t OFF_SORT  = OFF_PART;             // 2 MB (sorted src)
  const size_t OFF_OFFS  = OFF_PART + 2097152;   // 128 KB (CSR offsets)

  float* xw     = (float*)(ws + OFF_XW);
  float* h      = (float*)(ws + OFF_H);
  u32*   deg    = (u32*)  (ws + OFF_DEG);
  float* dinv   = (float*)(ws + OFF_DINV);
  float* scale  = (float*)(ws + OFF_SCALE);
  float* shift  = (float*)(ws + OFF_SHIFT);
  float* henc   = (float*)(ws + OFF_HENC);
  float* hdT    = (float*)(ws + OFF_HDT);
  float* p2     = (float*)(ws + OFF_P2);
  float* part   = (float*)(ws + OFF_PART);
  u32*   sorted = (u32*)  (ws + OFF_SORT);
  u32*   offs   = (u32*)  (ws + OFF_OFFS);

  k_xw       <<<4096, 256,  0, stream>>>(x, Wg, xw);
  k_buildcsr <<<16,   1024, 0, stream>>>(ei, offs, deg, dinv, sorted);
  k_gather   <<<512,  256,  0, stream>>>(sorted, offs, deg, dinv, xw, bg, h);
  k_bnfin    <<<16,   1024, 0, stream>>>(h, gamma, beta, scale, shift);

  // encoder: K=65536 in 512 chunks of 128 (tanh-norm fused), N=512
  k_gemvenc  <<<512, 256, 0, stream>>>(h, scale, shift, Wenc, part);
  k_encred1  <<<256, 256, 0, stream>>>(part, p2);
  k_encred2  <<<32,  256, 0, stream>>>(p2, benc, henc);

  k_headdec  <<<16, 512, 0, stream>>>(henc, Wmu, bmu, Wlv, blv, eps, Wd1, bd1, hdT, outp);

  // decoder: K=512 split into 4x128, 512 blocks, then reduce+bias
  k_gemvdec  <<<512, 256, 0, stream>>>(hdT, Wd2, part);
  k_decred   <<<1024, 256, 0, stream>>>((const float4*)part, (const float4*)bd2, (float4*)outp);
}